// Round 6
// baseline (1119.988 us; speedup 1.0000x reference)
//
#include <hip/hip_runtime.h>
#include <stdint.h>

// N=8192 samples, D=4096 statevector dim (fixed by reference)
#define NN 8192
#define DD 4096
#define BK 32           // K-step
#define NT (DD / BK)    // 128 K-steps
#define NBLK 64         // 8192 / 128
#define LDS_T 16384     // one tile: 128 rows x 128 B (re[32]|im[32] bf16, 8-slot XOR swizzle)
#define LDSBUF 32768    // A tile + B tile
#define NTILE 2080      // upper-tri incl diagonal: 64*65/2

typedef short bf16x8 __attribute__((ext_vector_type(8)));
typedef float f32x4  __attribute__((ext_vector_type(4)));
typedef uint16_t u16x4 __attribute__((ext_vector_type(4)));

#define GLOAD(g, l) __builtin_amdgcn_global_load_lds( \
    (__attribute__((address_space(1))) uint32_t*)(void*)(size_t)(g), \
    (__attribute__((address_space(3))) uint32_t*)(void*)(l), 16, 0, 0)

#define VMW6() asm volatile("s_waitcnt vmcnt(6)" ::: "memory")
#define VMW2() asm volatile("s_waitcnt vmcnt(2)" ::: "memory")
#define VMW0() asm volatile("s_waitcnt vmcnt(0)" ::: "memory")
#define SBAR() __builtin_amdgcn_s_barrier()
#define SCHED0() __builtin_amdgcn_sched_barrier(0)

__device__ __forceinline__ uint16_t f2bf(float x) {
  uint32_t u = __builtin_bit_cast(uint32_t, x);
  return (uint16_t)((u + 0x7fffu + ((u >> 16) & 1u)) >> 16);
}

__global__ void convert_kernel(const float* __restrict__ re, const float* __restrict__ im,
                               uint16_t* __restrict__ reb, uint16_t* __restrict__ imb) {
  size_t i = (size_t)blockIdx.x * blockDim.x + threadIdx.x;
  const size_t stride = (size_t)gridDim.x * blockDim.x;
  const size_t total = (size_t)NN * DD / 4;
  for (; i < total; i += stride) {
    float4 r = ((const float4*)re)[i];
    float4 m = ((const float4*)im)[i];
    u16x4 rb = { f2bf(r.x), f2bf(r.y), f2bf(r.z), f2bf(r.w) };
    u16x4 mb = { f2bf(m.x), f2bf(m.y), f2bf(m.z), f2bf(m.w) };
    ((u16x4*)reb)[i] = rb;
    ((u16x4*)imb)[i] = mb;
  }
}

// 128x128 tile of G per block-pair (bi, bj), bi <= bj. 4 waves (64x64 out each),
// double-buffered 64 KB LDS -> 2 blocks/CU. Conflict-free XOR-swizzled LDS (verified
// SQ_LDS_BANK_CONFLICT == 0). Round-6 schedule (T3+T4): counted vmcnt, NO vmcnt(0)
// in the main loop. Per step: issue A+B01(s+1); phases 0,1; vmcnt(6)+barrier
// (publishes B23(s), issued a full step earlier); issue B23(s+1); phases 2,3;
// vmcnt(2)+barrier (publishes A+B01(s+1), issued ~700cy earlier).
__global__ __launch_bounds__(256, 2) void gram_kernel(
    const uint16_t* __restrict__ reb, const uint16_t* __restrict__ imb,
    float* __restrict__ wts, float* __restrict__ fidp) {
  __shared__ alignas(16) char lds[2 * LDSBUF];  // 64 KB

  // XCD-aware bijective swizzle (2080 = 8*260)
  const int b = blockIdx.x;
  const int t = (b & 7) * 260 + (b >> 3);

  // t -> (bi, bj), bi <= bj (verified round 1)
  int bi = (int)(((float)(2 * NBLK + 1) -
                  sqrtf((float)((2 * NBLK + 1) * (2 * NBLK + 1) - 8 * t))) * 0.5f);
  if (bi < 0) bi = 0;
  if (bi > NBLK - 1) bi = NBLK - 1;
  while (bi > 0 && t < bi * NBLK - bi * (bi - 1) / 2) --bi;
  while (t >= (bi + 1) * NBLK - (bi + 1) * bi / 2) ++bi;
  const int bj = bi + (t - (bi * NBLK - bi * (bi - 1) / 2));

  const int brow = bi * 128, bcol = bj * 128;
  const int tid = threadIdx.x;
  const int lane = tid & 63;
  const int wid = tid >> 6;               // 4 waves
  const int wr = wid >> 1, wc = wid & 1;  // 2x2 wave grid, 64x64 out per wave
  const int t16 = tid * 16;

  // ---- staging source (pre-swizzled; LDS dest linear = round*4096 + tid*16) ----
  // LDS row r (128 B): physical slot p holds logical slot p ^ (r&7);
  // logical slots 0-3 = re chunks, 4-7 = im chunks.
  const int srow = tid >> 3;                     // 0..31 (rounds add 32)
  const int slog = (tid & 7) ^ (srow & 7);       // 32 ≡ 0 mod 8 -> constant across rounds
  const uint16_t* smat = (slog < 4) ? reb : imb;
  const int scol = (slog & 3) * 8;
  const uint16_t* spA = smat + (size_t)(brow + srow) * DD + scol;
  const uint16_t* spB = smat + (size_t)(bcol + srow) * DD + scol;
  const size_t r32 = (size_t)32 * DD;

  // A: all 4 rounds (rows 0-127). B01: rounds 0,2 (rows 0-31,64-95 = frags n0,n1 both wc).
  // B23: rounds 1,3 (rows 32-63,96-127 = frags n2,n3 both wc).
#define STAGE_A(s, bf) do { const size_t ko = (size_t)(s) * BK;                 \
    char* lb_ = lds + (bf) * LDSBUF + t16;                                      \
    GLOAD(spA + ko,           lb_);                                             \
    GLOAD(spA + ko + r32,     lb_ + 4096);                                      \
    GLOAD(spA + ko + 2 * r32, lb_ + 8192);                                      \
    GLOAD(spA + ko + 3 * r32, lb_ + 12288); } while (0)
#define STAGE_B01(s, bf) do { const size_t ko = (size_t)(s) * BK;               \
    char* lb_ = lds + (bf) * LDSBUF + LDS_T + t16;                              \
    GLOAD(spB + ko,           lb_);                                             \
    GLOAD(spB + ko + 2 * r32, lb_ + 8192); } while (0)
#define STAGE_B23(s, bf) do { const size_t ko = (size_t)(s) * BK;               \
    char* lb_ = lds + (bf) * LDSBUF + LDS_T + t16;                              \
    GLOAD(spB + ko + r32,     lb_ + 4096);                                      \
    GLOAD(spB + ko + 3 * r32, lb_ + 12288); } while (0)

  // ---- fragment read offsets (slot_phys = kg ^ (row&7), row&7 = fr&7) ----
  const int fr = lane & 15;
  const int kg = lane >> 4;
  const int reslot = (kg ^ (fr & 7)) << 4;   // re frag byte slot; im = reslot^64
  const int arow = (wr * 64 + fr) * 128;     // + m*2048
  const int brw  = (wc * 64 + fr) * 128;     // + n*2048

  f32x4 acc_re[4][4], acc_im[4][4];
  const f32x4 z4 = {0.f, 0.f, 0.f, 0.f};
#pragma unroll
  for (int m = 0; m < 4; ++m)
#pragma unroll
    for (int n = 0; n < 4; ++n) { acc_re[m][n] = z4; acc_im[m][n] = z4; }

#define MFMA16(n, brv, biv) do {                                                     \
    _Pragma("unroll") for (int m = 0; m < 4; ++m) {                                  \
      acc_re[m][n] = __builtin_amdgcn_mfma_f32_16x16x32_bf16(ar[m],  brv, acc_re[m][n], 0, 0, 0); \
      acc_re[m][n] = __builtin_amdgcn_mfma_f32_16x16x32_bf16(ai[m],  biv, acc_re[m][n], 0, 0, 0); \
      acc_im[m][n] = __builtin_amdgcn_mfma_f32_16x16x32_bf16(ai[m],  brv, acc_im[m][n], 0, 0, 0); \
      acc_im[m][n] = __builtin_amdgcn_mfma_f32_16x16x32_bf16(arn[m], biv, acc_im[m][n], 0, 0, 0); \
    } } while (0)

  // ---- prologue: full buffer 0, one-time drain ----
  STAGE_A(0, 0); STAGE_B01(0, 0); STAGE_B23(0, 0);
  VMW0();
  SBAR(); SCHED0();

  for (int s = 0; s < NT; ++s) {
    const char* la  = lds + (s & 1) * LDSBUF;
    const char* lbt = la + LDS_T;
    const int nb = (s & 1) ^ 1;

    // issue next step's A + B01 (6 loads; in flight across both barriers below)
    if (s + 1 < NT) { STAGE_A(s + 1, nb); STAGE_B01(s + 1, nb); }

    // ---- first half: A frags + B0,B1 ----
    bf16x8 ar[4], ai[4], arn[4];
#pragma unroll
    for (int m = 0; m < 4; ++m) {
      ar[m] = *(const bf16x8*)(la + arow + m * 2048 + reslot);
      ai[m] = *(const bf16x8*)(la + arow + m * 2048 + (reslot ^ 64));
    }
    bf16x8 br0 = *(const bf16x8*)(lbt + brw + 0 * 2048 + reslot);
    bf16x8 bi0 = *(const bf16x8*)(lbt + brw + 0 * 2048 + (reslot ^ 64));
    bf16x8 br1 = *(const bf16x8*)(lbt + brw + 1 * 2048 + reslot);
    bf16x8 bi1 = *(const bf16x8*)(lbt + brw + 1 * 2048 + (reslot ^ 64));
#pragma unroll
    for (int m = 0; m < 4; ++m) arn[m] = ar[m] ^ (short)0x8000;

    __builtin_amdgcn_s_setprio(1);
    MFMA16(0, br0, bi0);
    MFMA16(1, br1, bi1);
    __builtin_amdgcn_s_setprio(0);

    // publish B23(s): its 2 loads were issued mid-step s-1 (>= full half-step slack)
    if (s + 1 < NT) { VMW6(); } else { VMW0(); }
    SBAR(); SCHED0();

    // issue next step's B23 (2 loads)
    if (s + 1 < NT) STAGE_B23(s + 1, nb);

    // ---- second half: B2,B3 ----
    bf16x8 br2 = *(const bf16x8*)(lbt + brw + 2 * 2048 + reslot);
    bf16x8 bi2 = *(const bf16x8*)(lbt + brw + 2 * 2048 + (reslot ^ 64));
    bf16x8 br3 = *(const bf16x8*)(lbt + brw + 3 * 2048 + reslot);
    bf16x8 bi3 = *(const bf16x8*)(lbt + brw + 3 * 2048 + (reslot ^ 64));

    __builtin_amdgcn_s_setprio(1);
    MFMA16(2, br2, bi2);
    MFMA16(3, br3, bi3);
    __builtin_amdgcn_s_setprio(0);

    // publish A+B01(s+1) (issued at step top, ~700cy slack); B23(s+1) stays in flight
    VMW2();
    SBAR(); SCHED0();
  }

  // ---- epilogue (verified rounds 1-5) ----
  // C/D layout (16x16x32): col = lane&15, row = (lane>>4)*4 + reg
  const int grow0 = brow + wr * 64 + kg * 4;  // + m*16 + j
  const int gcol0 = bcol + wc * 64 + fr;      // + n*16

#pragma unroll
  for (int m = 0; m < 4; ++m) {
#pragma unroll
    for (int n = 0; n < 4; ++n) {
      const int gc = gcol0 + n * 16;
      f32x4 fv;
#pragma unroll
      for (int j = 0; j < 4; ++j) {
        float gr = acc_re[m][n][j];
        float gi = acc_im[m][n][j];
        fv[j] = gr * gr + gi * gi;
      }
#pragma unroll
      for (int j = 0; j < 4; ++j) {
        const int grow = grow0 + m * 16 + j;
        const float f = fv[j];
        fidp[(size_t)grow * NN + gc] = f;
        float w = 0.0f;
        if (grow < gc) w = (f >= 0.8f) ? 1.0f : ((f >= 0.5f) ? 0.5f : 0.0f);
        wts[(size_t)grow * NN + gc] = w;
      }
      if (bi != bj) {  // fid symmetric: mirror 4 contiguous rows at transposed addr
        *(f32x4*)(fidp + (size_t)gc * NN + grow0 + m * 16) = fv;
      }
    }
  }

  if (bi != bj) {
    // mirror block (bj,bi) of wts is strictly lower-triangular -> zeros
    const f32x4 zz = {0.f, 0.f, 0.f, 0.f};
    for (int i = tid; i < 4096; i += 256) {
      const int r = i >> 5, c4 = i & 31;
      *(f32x4*)(wts + (size_t)(bcol + r) * NN + brow + c4 * 4) = zz;
    }
  }
}

extern "C" void kernel_launch(void* const* d_in, const int* in_sizes, int n_in,
                              void* d_out, int out_size, void* d_ws, size_t ws_size,
                              hipStream_t stream) {
  const float* re = (const float*)d_in[0];
  const float* im = (const float*)d_in[1];
  float* out = (float*)d_out;

  uint16_t* reb = (uint16_t*)d_ws;
  uint16_t* imb = reb + (size_t)NN * DD;

  convert_kernel<<<2048, 256, 0, stream>>>(re, im, reb, imb);
  gram_kernel<<<NTILE, 256, 0, stream>>>(reb, imb, out, out + (size_t)NN * NN);
}